// Round 2
// baseline (494.313 us; speedup 1.0000x reference)
//
#include <hip/hip_runtime.h>
#include <stdint.h>

#define MDIM 8192
#define NDIM 4096
#define KDIM 4096
#define FINAL_SZ (NDIM * KDIM / 4)   // 4,194,304 packed bytes
#define BM 128
#define BN 128
#define BK 64

#define CVT_BLOCKS ((MDIM * KDIM / 8) / 256)     // 16384 blocks, 8 floats/thread
#define UNPACK_BLOCKS ((FINAL_SZ / 8) / 256)     // 2048 blocks, 8 bytes/thread

typedef __attribute__((ext_vector_type(8))) short short8;
typedef __attribute__((ext_vector_type(4))) float floatx4;

typedef const __attribute__((address_space(1))) void global_cv;
typedef __attribute__((address_space(3))) void lds_v;

__device__ __forceinline__ unsigned short f2bf_rne(float f) {
    union { float f; uint32_t u; } a; a.f = f;
    uint32_t u = a.u;
    u += 0x7FFFu + ((u >> 16) & 1u);           // round-to-nearest-even (finite normals)
    return (unsigned short)(u >> 16);
}

// code 0,1,2,3 -> bf16 bits of -1,0,1,2
__device__ __forceinline__ short code2bf(unsigned int c) {
    return (short)((0x40003F800000BF80ull >> (c * 16)) & 0xFFFFull);
}

// ---------- merged prep: x fp32->bf16 AND pw unpack->bf16 W, one dispatch ----------
__global__ void prep_kernel(const float* __restrict__ x, const void* __restrict__ pwv,
                            unsigned short* __restrict__ xb, unsigned short* __restrict__ wb) {
    const int b = blockIdx.x;
    if (b < CVT_BLOCKS) {
        // ---- x conversion: 8 floats per thread, 16B store
        int i = b * 256 + threadIdx.x;
        const float4* xin = (const float4*)x;
        float4 v0 = xin[2 * i];
        float4 v1 = xin[2 * i + 1];
        short8 o;
        o[0] = (short)f2bf_rne(v0.x); o[1] = (short)f2bf_rne(v0.y);
        o[2] = (short)f2bf_rne(v0.z); o[3] = (short)f2bf_rne(v0.w);
        o[4] = (short)f2bf_rne(v1.x); o[5] = (short)f2bf_rne(v1.y);
        o[6] = (short)f2bf_rne(v1.z); o[7] = (short)f2bf_rne(v1.w);
        *(short8*)(xb + (size_t)i * 8) = o;
    } else {
        // ---- layout detect (wave-uniform, globally consistent: all waves read the
        // same first 64 words; packed-uint8 random bytes make a word >255 w.p. ~1)
        unsigned int probe = ((const unsigned int*)pwv)[threadIdx.x & 63];
        bool packed = (__ballot(probe > 255u) != 0ull);

        int t = (b - CVT_BLOCKS) * 256 + threadIdx.x;   // 8 packed bytes per thread
        unsigned int lo, hi;
        if (packed) {
            uint2 u = ((const uint2*)pwv)[t];
            lo = u.x; hi = u.y;
        } else {  // int32-widened: one byte value per int
            int4 q0 = ((const int4*)pwv)[2 * t];
            int4 q1 = ((const int4*)pwv)[2 * t + 1];
            lo = (unsigned)(q0.x & 255) | ((unsigned)(q0.y & 255) << 8)
               | ((unsigned)(q0.z & 255) << 16) | ((unsigned)(q0.w & 255) << 24);
            hi = (unsigned)(q1.x & 255) | ((unsigned)(q1.y & 255) << 8)
               | ((unsigned)(q1.z & 255) << 16) | ((unsigned)(q1.w & 255) << 24);
        }
        int j  = t << 3;         // first byte index
        int r  = j >> 12;        // packed row 0..1023
        int ci = j & 4095;       // column (multiple of 8 -> 16B-aligned stores)
#pragma unroll
        for (int p = 0; p < 4; ++p) {
            short8 o;
            o[0] = code2bf((lo >> (2 * p)) & 3u);
            o[1] = code2bf((lo >> (8 + 2 * p)) & 3u);
            o[2] = code2bf((lo >> (16 + 2 * p)) & 3u);
            o[3] = code2bf((lo >> (24 + 2 * p)) & 3u);
            o[4] = code2bf((hi >> (2 * p)) & 3u);
            o[5] = code2bf((hi >> (8 + 2 * p)) & 3u);
            o[6] = code2bf((hi >> (16 + 2 * p)) & 3u);
            o[7] = code2bf((hi >> (24 + 2 * p)) & 3u);
            *(short8*)(wb + (((size_t)((p << 10) + r)) << 12) + ci) = o;  // w[p*1024+r][ci..]
        }
    }
}

// ---------- gemm: C = clip((A . B^T) * scale + bias), unchanged from R1 (932 TF) ----------
// A: x_bf16 [M][K] row-major, B: w_bf16 [N][K] row-major, C: fp32 [M][N]
// 128x128 tile, BK=64, 4 waves (2x2 of 64x64), 16x16x32 bf16 MFMA,
// global_load_lds width=16, XOR chunk swizzle on the GLOBAL side (conflicts=0 measured).
__global__ __launch_bounds__(256) void gemm_ternary(
    const unsigned short* __restrict__ A,
    const unsigned short* __restrict__ B,
    const float* __restrict__ scale,
    const float* __restrict__ bias,
    float* __restrict__ C) {
    __shared__ __align__(16) unsigned short lA[BM * BK];  // 16 KiB
    __shared__ __align__(16) unsigned short lB[BN * BK];  // 16 KiB

    const int tid  = threadIdx.x;
    const int lane = tid & 63;
    const int wave = tid >> 6;
    const int m0 = blockIdx.y * BM;
    const int n0 = blockIdx.x * BN;
    const int wm = (wave >> 1) * 64;
    const int wn = (wave & 1) * 64;

    const char* gA[4];
    const char* gB[4];
    unsigned short* lAd[4];
    unsigned short* lBd[4];
#pragma unroll
    for (int t = 0; t < 4; ++t) {
        int row  = wave * 32 + t * 8 + (lane >> 3);
        int clog = (lane & 7) ^ (row & 7);                // swizzled global 16B chunk
        gA[t] = (const char*)(A + (size_t)(m0 + row) * KDIM) + clog * 16;
        gB[t] = (const char*)(B + (size_t)(n0 + row) * KDIM) + clog * 16;
        lAd[t] = lA + (wave * 32 + t * 8) * 64;           // wave-uniform LDS base
        lBd[t] = lB + (wave * 32 + t * 8) * 64;
    }

    floatx4 acc[4][4];
#pragma unroll
    for (int i = 0; i < 4; ++i)
#pragma unroll
        for (int j = 0; j < 4; ++j)
            acc[i][j] = (floatx4){0.f, 0.f, 0.f, 0.f};

    for (int k0 = 0; k0 < KDIM; k0 += BK) {
#pragma unroll
        for (int t = 0; t < 4; ++t) {
            __builtin_amdgcn_global_load_lds((global_cv*)gA[t], (lds_v*)lAd[t], 16, 0, 0);
            __builtin_amdgcn_global_load_lds((global_cv*)gB[t], (lds_v*)lBd[t], 16, 0, 0);
            gA[t] += BK * 2;
            gB[t] += BK * 2;
        }
        __syncthreads();

#pragma unroll
        for (int kt = 0; kt < 2; ++kt) {
            short8 af[4], bfr[4];
#pragma unroll
            for (int i = 0; i < 4; ++i) {
                int rowA = wm + i * 16 + (lane & 15);
                int cA   = (kt * 4 + (lane >> 4)) ^ (rowA & 7);
                af[i] = *(const short8*)(lA + rowA * 64 + cA * 8);
                int rowB = wn + i * 16 + (lane & 15);
                int cB   = (kt * 4 + (lane >> 4)) ^ (rowB & 7);
                bfr[i] = *(const short8*)(lB + rowB * 64 + cB * 8);
            }
#pragma unroll
            for (int mi = 0; mi < 4; ++mi)
#pragma unroll
                for (int ni = 0; ni < 4; ++ni)
                    acc[mi][ni] = __builtin_amdgcn_mfma_f32_16x16x32_bf16(
                        af[mi], bfr[ni], acc[mi][ni], 0, 0, 0);
        }
        __syncthreads();
    }

    // epilogue: C/D layout col = lane&15 (n), row = (lane>>4)*4 + reg (m)
    float sc[4], bi[4];
#pragma unroll
    for (int ni = 0; ni < 4; ++ni) {
        int n  = n0 + wn + ni * 16 + (lane & 15);
        sc[ni] = scale[n];
        bi[ni] = bias[n];
    }
#pragma unroll
    for (int mi = 0; mi < 4; ++mi) {
#pragma unroll
        for (int r = 0; r < 4; ++r) {
            int m = m0 + wm + mi * 16 + (lane >> 4) * 4 + r;
            float* Crow = C + (size_t)m * NDIM;
#pragma unroll
            for (int ni = 0; ni < 4; ++ni) {
                int n = n0 + wn + ni * 16 + (lane & 15);
                float v = acc[mi][ni][r] * sc[ni] + bi[ni];
                v = fminf(100.f, fmaxf(-100.f, v));
                Crow[n] = v;
            }
        }
    }
}

extern "C" void kernel_launch(void* const* d_in, const int* in_sizes, int n_in,
                              void* d_out, int out_size, void* d_ws, size_t ws_size,
                              hipStream_t stream) {
    const float* x  = (const float*)d_in[0];
    const void*  pw = d_in[1];                 // packed uint8 OR int32-widened; device-detected
    const float* scale = (const float*)d_in[2];
    const float* bias  = (const float*)d_in[3];
    float* out = (float*)d_out;

    // workspace: [0, 64MiB) x_bf16 | [64MiB, 96MiB) w_bf16
    unsigned short* xb = (unsigned short*)d_ws;
    unsigned short* wb = xb + (size_t)MDIM * KDIM;

    prep_kernel<<<CVT_BLOCKS + UNPACK_BLOCKS, 256, 0, stream>>>(x, pw, xb, wb);

    dim3 grid(NDIM / BN, MDIM / BM);   // 32 x 64
    gemm_ternary<<<grid, 256, 0, stream>>>(xb, wb, scale, bias, out);
}

// Round 3
// 488.572 us; speedup vs baseline: 1.0117x; 1.0117x over previous
//
#include <hip/hip_runtime.h>
#include <stdint.h>

#define MDIM 8192
#define NDIM 4096
#define KDIM 4096
#define FINAL_SZ (NDIM * KDIM / 4)   // 4,194,304 packed bytes
#define BM 128
#define BN 128
#define BK 64

#define CVT_BLOCKS ((MDIM * KDIM / 8) / 256)     // 16384 blocks, 8 floats/thread
#define UNPACK_BLOCKS ((FINAL_SZ / 8) / 256)     // 2048 blocks, 8 bytes/thread

typedef __attribute__((ext_vector_type(8))) short short8;
typedef __attribute__((ext_vector_type(16))) float floatx16;

typedef const __attribute__((address_space(1))) void global_cv;
typedef __attribute__((address_space(3))) void lds_v;

__device__ __forceinline__ unsigned short f2bf_rne(float f) {
    union { float f; uint32_t u; } a; a.f = f;
    uint32_t u = a.u;
    u += 0x7FFFu + ((u >> 16) & 1u);           // round-to-nearest-even (finite normals)
    return (unsigned short)(u >> 16);
}

// code 0,1,2,3 -> bf16 bits of -1,0,1,2
__device__ __forceinline__ short code2bf(unsigned int c) {
    return (short)((0x40003F800000BF80ull >> (c * 16)) & 0xFFFFull);
}

// ---------- merged prep: x fp32->bf16 AND pw unpack->bf16 W, one dispatch ----------
__global__ void prep_kernel(const float* __restrict__ x, const void* __restrict__ pwv,
                            unsigned short* __restrict__ xb, unsigned short* __restrict__ wb) {
    const int b = blockIdx.x;
    if (b < CVT_BLOCKS) {
        int i = b * 256 + threadIdx.x;
        const float4* xin = (const float4*)x;
        float4 v0 = xin[2 * i];
        float4 v1 = xin[2 * i + 1];
        short8 o;
        o[0] = (short)f2bf_rne(v0.x); o[1] = (short)f2bf_rne(v0.y);
        o[2] = (short)f2bf_rne(v0.z); o[3] = (short)f2bf_rne(v0.w);
        o[4] = (short)f2bf_rne(v1.x); o[5] = (short)f2bf_rne(v1.y);
        o[6] = (short)f2bf_rne(v1.z); o[7] = (short)f2bf_rne(v1.w);
        *(short8*)(xb + (size_t)i * 8) = o;
    } else {
        // layout detect (wave-uniform, globally consistent)
        unsigned int probe = ((const unsigned int*)pwv)[threadIdx.x & 63];
        bool packed = (__ballot(probe > 255u) != 0ull);

        int t = (b - CVT_BLOCKS) * 256 + threadIdx.x;   // 8 packed bytes per thread
        unsigned int lo, hi;
        if (packed) {
            uint2 u = ((const uint2*)pwv)[t];
            lo = u.x; hi = u.y;
        } else {  // int32-widened: one byte value per int
            int4 q0 = ((const int4*)pwv)[2 * t];
            int4 q1 = ((const int4*)pwv)[2 * t + 1];
            lo = (unsigned)(q0.x & 255) | ((unsigned)(q0.y & 255) << 8)
               | ((unsigned)(q0.z & 255) << 16) | ((unsigned)(q0.w & 255) << 24);
            hi = (unsigned)(q1.x & 255) | ((unsigned)(q1.y & 255) << 8)
               | ((unsigned)(q1.z & 255) << 16) | ((unsigned)(q1.w & 255) << 24);
        }
        int j  = t << 3;
        int r  = j >> 12;        // packed row 0..1023
        int ci = j & 4095;       // column (x8 -> 16B-aligned stores)
#pragma unroll
        for (int p = 0; p < 4; ++p) {
            short8 o;
            o[0] = code2bf((lo >> (2 * p)) & 3u);
            o[1] = code2bf((lo >> (8 + 2 * p)) & 3u);
            o[2] = code2bf((lo >> (16 + 2 * p)) & 3u);
            o[3] = code2bf((lo >> (24 + 2 * p)) & 3u);
            o[4] = code2bf((hi >> (2 * p)) & 3u);
            o[5] = code2bf((hi >> (8 + 2 * p)) & 3u);
            o[6] = code2bf((hi >> (16 + 2 * p)) & 3u);
            o[7] = code2bf((hi >> (24 + 2 * p)) & 3u);
            *(short8*)(wb + (((size_t)((p << 10) + r)) << 12) + ci) = o;
        }
    }
}

// ---------- gemm: C = clip((A . B^T) * scale + bias) ----------
// R3 change: MFMA 32x32x16 (8.07 cyc, 2495 TF ubench) instead of 16x16x32
// (4.6 cyc, 2176 TF): same FLOP in ~17% fewer MFMA-issue cycles per K-step.
// 128x128 tile, BK=64, 4 waves (2x2 of 64x64, each 2x2 of 32x32 MFMA tiles),
// global_load_lds width=16, XOR chunk swizzle on the GLOBAL side (conflicts=0).
__global__ __launch_bounds__(256) void gemm_ternary(
    const unsigned short* __restrict__ A,
    const unsigned short* __restrict__ B,
    const float* __restrict__ scale,
    const float* __restrict__ bias,
    float* __restrict__ C) {
    __shared__ __align__(16) unsigned short lA[BM * BK];  // 16 KiB
    __shared__ __align__(16) unsigned short lB[BN * BK];  // 16 KiB

    const int tid  = threadIdx.x;
    const int lane = tid & 63;
    const int wave = tid >> 6;
    const int m0 = blockIdx.y * BM;
    const int n0 = blockIdx.x * BN;
    const int wm = (wave >> 1) * 64;
    const int wn = (wave & 1) * 64;

    const char* gA[4];
    const char* gB[4];
    unsigned short* lAd[4];
    unsigned short* lBd[4];
#pragma unroll
    for (int t = 0; t < 4; ++t) {
        int row  = wave * 32 + t * 8 + (lane >> 3);
        int clog = (lane & 7) ^ (row & 7);                // swizzled global 16B chunk
        gA[t] = (const char*)(A + (size_t)(m0 + row) * KDIM) + clog * 16;
        gB[t] = (const char*)(B + (size_t)(n0 + row) * KDIM) + clog * 16;
        lAd[t] = lA + (wave * 32 + t * 8) * 64;           // wave-uniform LDS base
        lBd[t] = lB + (wave * 32 + t * 8) * 64;
    }

    floatx16 acc[2][2];
#pragma unroll
    for (int i = 0; i < 2; ++i)
#pragma unroll
        for (int j = 0; j < 2; ++j)
            acc[i][j] = (floatx16)(0.f);

    for (int k0 = 0; k0 < KDIM; k0 += BK) {
#pragma unroll
        for (int t = 0; t < 4; ++t) {
            __builtin_amdgcn_global_load_lds((global_cv*)gA[t], (lds_v*)lAd[t], 16, 0, 0);
            __builtin_amdgcn_global_load_lds((global_cv*)gB[t], (lds_v*)lBd[t], 16, 0, 0);
            gA[t] += BK * 2;
            gB[t] += BK * 2;
        }
        __syncthreads();

#pragma unroll
        for (int kt = 0; kt < 4; ++kt) {   // four K=16 slices of the BK=64 tile
            short8 af[2], bfr[2];
#pragma unroll
            for (int i = 0; i < 2; ++i) {
                // A-frag 32x32x16: lane holds A[m = lane&31][k = kt*16 + (lane>>5)*8 + j]
                int rowA = wm + i * 32 + (lane & 31);
                int cA   = (kt * 2 + (lane >> 5)) ^ (rowA & 7);
                af[i] = *(const short8*)(lA + rowA * 64 + cA * 8);
                int rowB = wn + i * 32 + (lane & 31);
                int cB   = (kt * 2 + (lane >> 5)) ^ (rowB & 7);
                bfr[i] = *(const short8*)(lB + rowB * 64 + cB * 8);
            }
#pragma unroll
            for (int mi = 0; mi < 2; ++mi)
#pragma unroll
                for (int ni = 0; ni < 2; ++ni)
                    acc[mi][ni] = __builtin_amdgcn_mfma_f32_32x32x16_bf16(
                        af[mi], bfr[ni], acc[mi][ni], 0, 0, 0);
        }
        __syncthreads();
    }

    // epilogue: 32x32 C/D layout (m74/m101-verified):
    //   n = lane&31, m = (reg&3) + 8*(reg>>2) + 4*(lane>>5)
    float sc[2], bi[2];
#pragma unroll
    for (int ni = 0; ni < 2; ++ni) {
        int n  = n0 + wn + ni * 32 + (lane & 31);
        sc[ni] = scale[n];
        bi[ni] = bias[n];
    }
#pragma unroll
    for (int mi = 0; mi < 2; ++mi) {
#pragma unroll
        for (int r = 0; r < 16; ++r) {
            int m = m0 + wm + mi * 32 + 4 * (lane >> 5) + (r & 3) + 8 * (r >> 2);
            float* Crow = C + (size_t)m * NDIM;
#pragma unroll
            for (int ni = 0; ni < 2; ++ni) {
                int n = n0 + wn + ni * 32 + (lane & 31);
                float v = acc[mi][ni][r] * sc[ni] + bi[ni];
                v = fminf(100.f, fmaxf(-100.f, v));
                Crow[n] = v;
            }
        }
    }
}

extern "C" void kernel_launch(void* const* d_in, const int* in_sizes, int n_in,
                              void* d_out, int out_size, void* d_ws, size_t ws_size,
                              hipStream_t stream) {
    const float* x  = (const float*)d_in[0];
    const void*  pw = d_in[1];                 // packed uint8 OR int32-widened; device-detected
    const float* scale = (const float*)d_in[2];
    const float* bias  = (const float*)d_in[3];
    float* out = (float*)d_out;

    // workspace: [0, 64MiB) x_bf16 | [64MiB, 96MiB) w_bf16
    unsigned short* xb = (unsigned short*)d_ws;
    unsigned short* wb = xb + (size_t)MDIM * KDIM;

    prep_kernel<<<CVT_BLOCKS + UNPACK_BLOCKS, 256, 0, stream>>>(x, pw, xb, wb);

    dim3 grid(NDIM / BN, MDIM / BM);   // 32 x 64
    gemm_ternary<<<grid, 256, 0, stream>>>(xb, wb, scale, bias, out);
}